// Round 9
// baseline (294.302 us; speedup 1.0000x reference)
//
#include <hip/hip_runtime.h>

#define B_ 16
#define K_ 20
#define H_ 256
#define W_ 256
#define HW_ (H_*W_)
#define BK_ (B_*K_)
#define TH_ 64          // rows per BLOCK strip (4 strips/image)
#define BATCH_ 8        // rows per barrier phase
#define NBLK_FUSED_ (4*K_*B_)   // fused grid = 1280 blocks (= exact residency capacity)

// ws layout (floats):
//   statsP [4 sg][4 q][BK_] = 5120   (plain stores, no pre-zero needed)
//   ndP    [NBLK][2]        = 2560
//   arrive [BK_] (ints)     = 320    (zeroed by zero_k)
//   cnt    (unsigned)       = 1      (zeroed by zero_k)
#define WS_ND_   (16*BK_)                  // 5120
#define WS_ARR_  (WS_ND_ + 2*NBLK_FUSED_)  // 7680
#define WS_CNT_  (WS_ARR_ + BK_)           // 8000

// Gaussian taps exp(-d^2/50), d=1..4 (symmetric: 4 distinct + center 1.0)
#define G1T 0.980198673f
#define G2T 0.923116346f
#define G3T 0.835270211f
#define G4T 0.726149037f

__device__ __forceinline__ float rfl(float v) {   // force value into SGPR
    return __int_as_float(__builtin_amdgcn_readfirstlane(__float_as_int(v)));
}

__global__ __launch_bounds__(256) void zero_k(float* ws) {
    const int i = blockIdx.x * 256 + threadIdx.x;
    if (i < BK_ + 1) ((unsigned*)(ws + WS_ARR_))[i] = 0u;   // arrive[] + cnt
}

// ---------------------------------------------------------------------------
// fused_k = PHASE A (strip stats + per-bk spin sync) + PHASE B (round-8 body).
//   Phase A: block sums l, l*i0, l*i1, l*i2 over its own 64-row strip
//   (float4 streaming — the same data phase B re-reads, so L2/L3 get warmed),
//   plain-stores 4 partials, device-fence, atomicAdd(arrive[bk]). Thread 0
//   spins (acquire, agent scope) until all 4 strips arrived. Safe: grid ==
//   exact co-residency capacity (5 blocks/CU by VGPR & LDS), and bk-peers
//   are bids {n,n+8,n+16,n+24} — dispatched adjacently.
//   Phase B: adjoint blur (num = sum (l*w)*blur(l), den = sum w*blur(l)),
//   8-row batches, raw s_barrier (lgkmcnt-only drain) so prefetch loads
//   survive the barrier (validated round 8).
// grid: 1280 blocks 1D, bijective XCD-chunk swizzle (1280 % 8 == 0).
// ---------------------------------------------------------------------------
#define CAT(m) (((m) < 8) ? ring[(m)&7] : PL[(m)&7])

__global__ __launch_bounds__(256) void fused_k(const float* __restrict__ labels,
                                               const float* __restrict__ inputs,
                                               float* __restrict__ ws,
                                               float* __restrict__ out) {
    const int x = threadIdx.x;            // column
    const int lane = x & 63, widx = x >> 6;
    const int bid = blockIdx.x;
    const int swz = (bid & 7) * (NBLK_FUSED_ / 8) + (bid >> 3);
    const int b   = swz / (4 * K_);
    const int rem = swz - b * (4 * K_);
    const int k   = rem >> 2;
    const int sg  = rem & 3;
    const int bk  = b * K_ + k;
    const int r0  = sg * TH_;

    const float* lb  = labels + (size_t)bk * HW_;
    const float* i0p = inputs + (size_t)b * 3 * HW_;
    const float* i1p = i0p + HW_;
    const float* i2p = i1p + HW_;

    __shared__ float sv[2][BATCH_][W_ + 8];   // pads [0..3], [W+4..W+7]
    __shared__ float sred[4][4];
    if (x < 128) {                            // 2 buf x 8 rows x 8 pad cols
        const int bu = x >> 6, j = (x >> 3) & 7, p = x & 7;
        const int col = (p < 4) ? p : (W_ + p);
        sv[bu][j][col] = 0.f;
    }

    // ================= PHASE A: strip stats =================
    {
        const float4* l4 = (const float4*)lb  + r0 * (W_/4);
        const float4* p0 = (const float4*)i0p + r0 * (W_/4);
        const float4* p1 = (const float4*)i1p + r0 * (W_/4);
        const float4* p2 = (const float4*)i2p + r0 * (W_/4);
        float4 aL = make_float4(0.f,0.f,0.f,0.f), a0 = aL, a1 = aL, a2 = aL;
#pragma unroll 2
        for (int it = 0; it < (TH_ * W_ / 4) / 256; ++it) {   // 16 iters
            const int idx = it * 256 + x;
            const float4 l = l4[idx];
            const float4 q0 = p0[idx];
            const float4 q1 = p1[idx];
            const float4 q2 = p2[idx];
            aL.x += l.x; aL.y += l.y; aL.z += l.z; aL.w += l.w;
            a0.x = fmaf(l.x,q0.x,a0.x); a0.y = fmaf(l.y,q0.y,a0.y);
            a0.z = fmaf(l.z,q0.z,a0.z); a0.w = fmaf(l.w,q0.w,a0.w);
            a1.x = fmaf(l.x,q1.x,a1.x); a1.y = fmaf(l.y,q1.y,a1.y);
            a1.z = fmaf(l.z,q1.z,a1.z); a1.w = fmaf(l.w,q1.w,a1.w);
            a2.x = fmaf(l.x,q2.x,a2.x); a2.y = fmaf(l.y,q2.y,a2.y);
            a2.z = fmaf(l.z,q2.z,a2.z); a2.w = fmaf(l.w,q2.w,a2.w);
        }
        float v[4] = {(aL.x+aL.y)+(aL.z+aL.w), (a0.x+a0.y)+(a0.z+a0.w),
                      (a1.x+a1.y)+(a1.z+a1.w), (a2.x+a2.y)+(a2.z+a2.w)};
#pragma unroll
        for (int q = 0; q < 4; ++q)
            for (int o = 32; o > 0; o >>= 1) v[q] += __shfl_down(v[q], o);
        if (lane == 0) { sred[widx][0]=v[0]; sred[widx][1]=v[1]; sred[widx][2]=v[2]; sred[widx][3]=v[3]; }
        __syncthreads();
        if (x == 0) {
#pragma unroll
            for (int q = 0; q < 4; ++q)
                ws[(sg * 4 + q) * BK_ + bk] =
                    sred[0][q] + sred[1][q] + sred[2][q] + sred[3][q];
            __threadfence();                               // partials visible device-wide
            atomicAdd((int*)(ws + WS_ARR_) + bk, 1);       // device-scope arrival
            int* arr = (int*)(ws + WS_ARR_) + bk;
            while (__hip_atomic_load(arr, __ATOMIC_ACQUIRE, __HIP_MEMORY_SCOPE_AGENT) < 4)
                __builtin_amdgcn_s_sleep(2);
        }
        __syncthreads();                                   // all threads wait on thread 0
    }

    // ---- class mean from the 4 strips' partials ----
    float s0 = 0.f, s1 = 0.f, s2 = 0.f, s3 = 0.f;
#pragma unroll
    for (int g = 0; g < 4; ++g) {
        s0 += ws[(g*4+0)*BK_ + bk]; s1 += ws[(g*4+1)*BK_ + bk];
        s2 += ws[(g*4+2)*BK_ + bk]; s3 += ws[(g*4+3)*BK_ + bk];
    }
    const float dnv = s0 + 1e-5f * (float)HW_;
    const float c0 = s1 / dnv, c1 = s2 / dnv, c2 = s3 / dnv;
    const float tc0 = rfl(2.f * c0), tc1 = rfl(2.f * c1), tc2 = rfl(2.f * c2);
    const float m2v = rfl(c0*c0 + c1*c1 + c2*c2);

    // ================= PHASE B: round-8 body (unchanged) =================
    float ring[8], PL[8], PW[8];
#pragma unroll
    for (int i = 0; i < 8; ++i) {             // rows r0-4 .. r0+3
        const int gr = r0 - 4 + i;
        ring[i] = (gr >= 0) ? lb[gr * W_ + x] : 0.f;
    }
#pragma unroll
    for (int i = 0; i < 8; ++i)               // rows r0+4 .. r0+11 (in range)
        PL[i] = lb[(r0 + 4 + i) * W_ + x];
#pragma unroll
    for (int i = 0; i < 8; ++i) {             // weights rows r0 .. r0+7
        const int r = r0 + i;
        const float a0 = i0p[r * W_ + x], a1 = i1p[r * W_ + x], a2 = i2p[r * W_ + x];
        const float d = fmaf(a0, a0 - tc0, fmaf(a1, a1 - tc1, fmaf(a2, a2 - tc2, m2v)));
        PW[i] = __expf(-d * d);               // SIGMA_2 = 1
    }
    __syncthreads();                          // pads + phase-A LDS reuse safe

    float num = 0.f, den = 0.f;
#pragma unroll 1
    for (int bt = 0; bt < TH_ / BATCH_; ++bt) {
        const int R = r0 + bt * BATCH_;
        const int bf = bt & 1;
        // ---- 1. issue next-batch loads (stay in flight across the barrier) --
        float NL[8];
#pragma unroll
        for (int i = 0; i < 8; ++i) {         // labels rows R+12..R+19, 0 if OOB
            const int gr = R + 12 + i;
            NL[i] = (gr < H_) ? lb[gr * W_ + x] : 0.f;
        }
        float a0v[8], a1v[8], a2v[8];
#pragma unroll
        for (int i = 0; i < 8; ++i) {         // inputs rows R+8..R+15 (clamped; OOB unused)
            int r = R + 8 + i; r = (r < H_) ? r : H_ - 1;
            a0v[i] = i0p[r * W_ + x]; a1v[i] = i1p[r * W_ + x]; a2v[i] = i2p[r * W_ + x];
        }
        // ---- 2. vertical 9-tap for 8 rows from ring||PL -> LDS ----
#pragma unroll
        for (int j = 0; j < 8; ++j) {
            const float v = fmaf(G4T, CAT(j) + CAT(j+8),
                            fmaf(G3T, CAT(j+1) + CAT(j+7),
                            fmaf(G2T, CAT(j+2) + CAT(j+6),
                            fmaf(G1T, CAT(j+3) + CAT(j+5), CAT(j+4)))));
            sv[bf][j][4 + x] = v;
        }
        // ---- 3. RAW barrier: drain LDS only; global loads stay in flight ----
        asm volatile("s_waitcnt lgkmcnt(0)" ::: "memory");
        __builtin_amdgcn_s_barrier();
        asm volatile("" ::: "memory");
        // ---- 4. h-blur + combine for 8 rows ----
#pragma unroll
        for (int j = 0; j < 8; ++j) {
            const float* s = &sv[bf][j][x];
            const float bl = fmaf(G4T, s[0] + s[8],
                             fmaf(G3T, s[1] + s[7],
                             fmaf(G2T, s[2] + s[6],
                             fmaf(G1T, s[3] + s[5], s[4]))));
            const float t = PW[j] * bl;
            den += t;
            num = fmaf(CAT(j+4), t, num);     // raw label at row R+j
        }
        // ---- 5. next weights + rotate state (first use of step-1 loads) ----
#pragma unroll
        for (int i = 0; i < 8; ++i) {
            const float d = fmaf(a0v[i], a0v[i] - tc0,
                            fmaf(a1v[i], a1v[i] - tc1,
                            fmaf(a2v[i], a2v[i] - tc2, m2v)));
            const float w = __expf(-d * d);
            ring[i] = PL[i]; PL[i] = NL[i]; PW[i] = w;
        }
    }

    // ---- block reduce + last-block finalize ----
    for (int o = 32; o > 0; o >>= 1) { num += __shfl_down(num, o); den += __shfl_down(den, o); }
    __shared__ float rb[4][2];
    __shared__ unsigned sdone;
    __syncthreads();
    if (lane == 0) { rb[widx][0] = num; rb[widx][1] = den; }
    __syncthreads();
    if (x == 0) {
        const float fn = rb[0][0] + rb[1][0] + rb[2][0] + rb[3][0];
        const float fd = rb[0][1] + rb[1][1] + rb[2][1] + rb[3][1];
        float2* nd2 = (float2*)(ws + WS_ND_);
        nd2[k * 64 + b * 4 + sg] = make_float2(fn, fd);
        __threadfence();
        sdone = atomicAdd((unsigned*)(ws + WS_CNT_), 1u);
    }
    __syncthreads();
    if (sdone == (unsigned)(NBLK_FUSED_ - 1)) {
        __threadfence();
        if (x < 64) {
            float term = 0.f;
            if (x < K_) {
                const float2* nd2 = (const float2*)(ws + WS_ND_);
                float ns = 0.f, ds = 0.f;
                for (int i = 0; i < 64; ++i) {
                    const float2 v = nd2[x * 64 + i];
                    ns += v.x; ds += v.y;
                }
                term = fabsf(ns / (ds + 1e-6f));
            }
            for (int o = 32; o > 0; o >>= 1) term += __shfl_down(term, o);
            if (x == 0) out[0] = (float)K_ - term;
        }
    }
}

extern "C" void kernel_launch(void* const* d_in, const int* in_sizes, int n_in,
                              void* d_out, int out_size, void* d_ws, size_t ws_size,
                              hipStream_t stream) {
    const float* labels = (const float*)d_in[0];
    const float* inputs = (const float*)d_in[1];
    float* ws = (float*)d_ws;   // needs WS_CNT_+1 floats ~= 32 KB

    zero_k<<<2, 256, 0, stream>>>(ws);
    fused_k<<<NBLK_FUSED_, 256, 0, stream>>>(labels, inputs, ws, (float*)d_out);
}

// Round 10
// 204.546 us; speedup vs baseline: 1.4388x; 1.4388x over previous
//
#include <hip/hip_runtime.h>

#define B_ 16
#define K_ 20
#define H_ 256
#define W_ 256
#define HW_ (H_*W_)
#define BK_ (B_*K_)
#define TH_ 32          // rows per strip (8 strips/image)
#define BATCH_ 8        // rows per barrier phase
#define KT_ 5           // stats: classes per block
#define SCH_ 16         // stats: row-chunks (16 rows each) -> 1024 blocks
#define NSTR_ 8         // strips per image
#define NKP_ 10         // k-pairs
#define NBLK_FUSED_ (NSTR_*NKP_*B_)   // 1280 blocks

// ws layout (floats): statsP [SCH_][4][BK_] | ndP [K_][B_*NSTR_][2] | cnt
#define WS_ND_   (SCH_*4*BK_)              // 10240
#define WS_CNT_  (WS_ND_ + 2*K_*B_*NSTR_)  // +5120

// Gaussian taps exp(-d^2/50), d=1..4 (symmetric: 4 distinct + center 1.0)
#define G1T 0.980198673f
#define G2T 0.923116346f
#define G3T 0.835270211f
#define G4T 0.726149037f

__device__ __forceinline__ float rfl(float v) {   // force value into SGPR
    return __int_as_float(__builtin_amdgcn_readfirstlane(__float_as_int(v)));
}

// ---------------------------------------------------------------------------
// stats_k: unchanged from round 8 (validated). Per-chunk partials, no atomics.
// ---------------------------------------------------------------------------
__global__ __launch_bounds__(256) void stats_k(const float* __restrict__ labels,
                                               const float* __restrict__ inputs,
                                               float* __restrict__ ws) {
    const int x = threadIdx.x;
    const int chunk = blockIdx.x;
    const int kt = blockIdx.y;
    const int b  = blockIdx.z;
    const int k0 = kt * KT_;
    if (chunk == 0 && kt == 0 && b == 0 && x == 0)
        ((unsigned*)(ws + WS_CNT_))[0] = 0u;   // reset fused completion counter

    const int cbase = chunk * (16 * W_ / 4);
    const float4* in0 = (const float4*)inputs + (size_t)b * 3 * (HW_/4) + cbase;
    const float4* in1 = in0 + (HW_/4);
    const float4* in2 = in1 + (HW_/4);
    const float4* lb  = (const float4*)labels + (size_t)(b * K_ + k0) * (HW_/4) + cbase;

    float acc[KT_][4];
#pragma unroll
    for (int kk = 0; kk < KT_; ++kk)
        acc[kk][0] = acc[kk][1] = acc[kk][2] = acc[kk][3] = 0.f;

#pragma unroll
    for (int it = 0; it < 4; ++it) {
        const int idx = it * 256 + x;
        const float4 a0 = in0[idx];
        const float4 a1 = in1[idx];
        const float4 a2 = in2[idx];
        float4 lv[KT_];
#pragma unroll
        for (int kk = 0; kk < KT_; ++kk) lv[kk] = lb[kk * (HW_/4) + idx];
#pragma unroll
        for (int kk = 0; kk < KT_; ++kk) {
            const float4 l = lv[kk];
            acc[kk][0] += (l.x + l.y) + (l.z + l.w);
            acc[kk][1] += fmaf(l.w, a0.w, fmaf(l.z, a0.z, fmaf(l.y, a0.y, l.x * a0.x)));
            acc[kk][2] += fmaf(l.w, a1.w, fmaf(l.z, a1.z, fmaf(l.y, a1.y, l.x * a1.x)));
            acc[kk][3] += fmaf(l.w, a2.w, fmaf(l.z, a2.z, fmaf(l.y, a2.y, l.x * a2.x)));
        }
    }

#pragma unroll
    for (int kk = 0; kk < KT_; ++kk)
#pragma unroll
        for (int q = 0; q < 4; ++q)
            for (int o = 32; o > 0; o >>= 1)
                acc[kk][q] += __shfl_down(acc[kk][q], o);

    __shared__ float sred[4][KT_][4];
    const int widx = x >> 6, lane = x & 63;
    if (lane == 0)
#pragma unroll
        for (int kk = 0; kk < KT_; ++kk)
#pragma unroll
            for (int q = 0; q < 4; ++q) sred[widx][kk][q] = acc[kk][q];
    __syncthreads();
    if (x < KT_ * 4) {
        const int kk = x >> 2, q = x & 3;
        const float v = sred[0][kk][q] + sred[1][kk][q] + sred[2][kk][q] + sred[3][kk][q];
        ws[(chunk * 4 + q) * BK_ + b * K_ + k0 + kk] = v;
    }
}

// ---------------------------------------------------------------------------
// fused_k, K-PAIRED (KT=2) adjoint form: one block computes TWO classes from
// ONE pass over the inputs stream (inputs were 2/3 of VMEM bytes, re-read by
// every k-block -> halved). num_k = sum (l_k*w_k)*blur(l_k),
// den_k = sum w_k*blur(l_k). Weights stored as d-values (dv), exp inline.
// 32-row strips, 8-row batches (4/block). Two RAW barriers per batch:
// write->bar1 (lgkm only)->read/combine->bar2; global prefetch loads survive
// both (counted vmcnt at first use, round-8 validated). Single-buffered LDS
// per k (bar2 protects overwrite; reads are register-consumed before bar2).
// grid: 1280 blocks 1D, bijective XCD-chunk swizzle (1280 % 8 == 0).
// ---------------------------------------------------------------------------
#define CAT0(m) (((m) < 8) ? ring0[(m)&7] : PL0[(m)&7])
#define CAT1(m) (((m) < 8) ? ring1[(m)&7] : PL1[(m)&7])

__global__ __launch_bounds__(256) void fused_k(const float* __restrict__ labels,
                                               const float* __restrict__ inputs,
                                               float* __restrict__ ws,
                                               float* __restrict__ out) {
    const int x = threadIdx.x;            // column
    const int lane = x & 63, widx = x >> 6;
    const int bid = blockIdx.x;
    const int swz = (bid & 7) * (NBLK_FUSED_ / 8) + (bid >> 3);
    const int b   = swz / (NSTR_ * NKP_);
    const int rem = swz - b * (NSTR_ * NKP_);
    const int kp  = rem >> 3;             // 0..9
    const int sg  = rem & 7;              // 0..7
    const int bk0 = b * K_ + kp * 2;
    const int r0  = sg * TH_;

    // ---- class means for BOTH classes (uniform -> SGPRs) ----
    float tcx[2], tcy[2], tcz[2], m2a[2];
#pragma unroll
    for (int kk = 0; kk < 2; ++kk) {
        float s0 = 0.f, s1 = 0.f, s2 = 0.f, s3 = 0.f;
#pragma unroll
        for (int c = 0; c < SCH_; ++c) {
            const float* p = ws + c * 4 * BK_;
            s0 += p[bk0+kk]; s1 += p[BK_ + bk0+kk];
            s2 += p[2*BK_ + bk0+kk]; s3 += p[3*BK_ + bk0+kk];
        }
        const float dnv = s0 + 1e-5f * (float)HW_;
        const float c0 = s1 / dnv, c1 = s2 / dnv, c2 = s3 / dnv;
        tcx[kk] = rfl(2.f * c0); tcy[kk] = rfl(2.f * c1); tcz[kk] = rfl(2.f * c2);
        m2a[kk] = rfl(c0*c0 + c1*c1 + c2*c2);
    }

    const float* lb0 = labels + (size_t)bk0 * HW_;
    const float* lb1 = lb0 + HW_;
    const float* i0p = inputs + (size_t)b * 3 * HW_;
    const float* i1p = i0p + HW_;
    const float* i2p = i1p + HW_;

    __shared__ float sv[2][BATCH_][W_ + 8];   // [k][row]; pads 0..3, W+4..W+7
    if (x < 128) {
        const int kk = x >> 6, j = (x >> 3) & 7, p = x & 7;
        const int col = (p < 4) ? p : (W_ + p);
        sv[kk][j][col] = 0.f;
    }

    // ---- prologue: label rings (rows r0-4..r0+11 per k) + d-values rows r0..r0+7
    float ring0[8], ring1[8], PL0[8], PL1[8], dv[2][8];
#pragma unroll
    for (int i = 0; i < 8; ++i) {
        const int gr = r0 - 4 + i;
        ring0[i] = (gr >= 0) ? lb0[gr * W_ + x] : 0.f;
        ring1[i] = (gr >= 0) ? lb1[gr * W_ + x] : 0.f;
    }
#pragma unroll
    for (int i = 0; i < 8; ++i) {             // rows r0+4..r0+11 (<=235, in range)
        PL0[i] = lb0[(r0 + 4 + i) * W_ + x];
        PL1[i] = lb1[(r0 + 4 + i) * W_ + x];
    }
#pragma unroll
    for (int i = 0; i < 8; ++i) {             // d at rows r0..r0+7
        const int r = r0 + i;
        const float a0 = i0p[r * W_ + x], a1 = i1p[r * W_ + x], a2 = i2p[r * W_ + x];
        const float x2 = fmaf(a0, a0, fmaf(a1, a1, a2 * a2));
#pragma unroll
        for (int kk = 0; kk < 2; ++kk)
            dv[kk][i] = fmaf(-a0, tcx[kk], fmaf(-a1, tcy[kk], fmaf(-a2, tcz[kk], x2 + m2a[kk])));
    }
    __syncthreads();                          // pads visible (full sync, once)

    float num0 = 0.f, den0 = 0.f, num1 = 0.f, den1 = 0.f;
#pragma unroll 1
    for (int bt = 0; bt < TH_ / BATCH_; ++bt) {
        const int R = r0 + bt * BATCH_;
        // ---- 1. issue next-batch loads (survive both barriers) ----
        float NL0[8], NL1[8];
#pragma unroll
        for (int i = 0; i < 8; ++i) {         // labels rows R+12..R+19, 0 if OOB
            const int gr = R + 12 + i;
            const bool in = (gr < H_);
            NL0[i] = in ? lb0[gr * W_ + x] : 0.f;
            NL1[i] = in ? lb1[gr * W_ + x] : 0.f;
        }
        float a0v[8], a1v[8], a2v[8];
#pragma unroll
        for (int i = 0; i < 8; ++i) {         // inputs rows R+8..R+15 (clamped; OOB unused)
            int r = R + 8 + i; r = (r < H_) ? r : H_ - 1;
            a0v[i] = i0p[r * W_ + x]; a1v[i] = i1p[r * W_ + x]; a2v[i] = i2p[r * W_ + x];
        }
        // ---- 2. vertical 9-tap for 8 rows x 2 classes -> LDS ----
#pragma unroll
        for (int j = 0; j < 8; ++j) {
            sv[0][j][4 + x] = fmaf(G4T, CAT0(j) + CAT0(j+8),
                              fmaf(G3T, CAT0(j+1) + CAT0(j+7),
                              fmaf(G2T, CAT0(j+2) + CAT0(j+6),
                              fmaf(G1T, CAT0(j+3) + CAT0(j+5), CAT0(j+4)))));
            sv[1][j][4 + x] = fmaf(G4T, CAT1(j) + CAT1(j+8),
                              fmaf(G3T, CAT1(j+1) + CAT1(j+7),
                              fmaf(G2T, CAT1(j+2) + CAT1(j+6),
                              fmaf(G1T, CAT1(j+3) + CAT1(j+5), CAT1(j+4)))));
        }
        // ---- 3. RAW barrier 1: drain LDS writes only ----
        asm volatile("s_waitcnt lgkmcnt(0)" ::: "memory");
        __builtin_amdgcn_s_barrier();
        asm volatile("" ::: "memory");
        // ---- 4. h-blur + weight + combine, both classes ----
#pragma unroll
        for (int j = 0; j < 8; ++j) {
            const float* s0p = &sv[0][j][x];
            const float bl0 = fmaf(G4T, s0p[0] + s0p[8],
                              fmaf(G3T, s0p[1] + s0p[7],
                              fmaf(G2T, s0p[2] + s0p[6],
                              fmaf(G1T, s0p[3] + s0p[5], s0p[4]))));
            const float* s1p = &sv[1][j][x];
            const float bl1 = fmaf(G4T, s1p[0] + s1p[8],
                              fmaf(G3T, s1p[1] + s1p[7],
                              fmaf(G2T, s1p[2] + s1p[6],
                              fmaf(G1T, s1p[3] + s1p[5], s1p[4]))));
            const float w0 = __expf(-dv[0][j] * dv[0][j]);
            const float w1 = __expf(-dv[1][j] * dv[1][j]);
            const float t0 = w0 * bl0;
            const float t1 = w1 * bl1;
            den0 += t0; den1 += t1;
            num0 = fmaf(CAT0(j+4), t0, num0);
            num1 = fmaf(CAT1(j+4), t1, num1);
        }
        // ---- 5. RAW barrier 2: reads done (register-consumed above) before
        //         next batch overwrites sv. No vmcnt/lgkm drain needed. ----
        __builtin_amdgcn_s_barrier();
        asm volatile("" ::: "memory");
        // ---- 6. next d-values + rotate (first use of step-1 loads) ----
#pragma unroll
        for (int i = 0; i < 8; ++i) {
            const float a0 = a0v[i], a1 = a1v[i], a2 = a2v[i];
            const float x2 = fmaf(a0, a0, fmaf(a1, a1, a2 * a2));
            dv[0][i] = fmaf(-a0, tcx[0], fmaf(-a1, tcy[0], fmaf(-a2, tcz[0], x2 + m2a[0])));
            dv[1][i] = fmaf(-a0, tcx[1], fmaf(-a1, tcy[1], fmaf(-a2, tcz[1], x2 + m2a[1])));
            ring0[i] = PL0[i]; PL0[i] = NL0[i];
            ring1[i] = PL1[i]; PL1[i] = NL1[i];
        }
    }

    // ---- block reduce + last-block finalize ----
    for (int o = 32; o > 0; o >>= 1) {
        num0 += __shfl_down(num0, o); den0 += __shfl_down(den0, o);
        num1 += __shfl_down(num1, o); den1 += __shfl_down(den1, o);
    }
    __shared__ float rb[4][4];
    __shared__ unsigned sdone;
    __syncthreads();
    if (lane == 0) { rb[widx][0] = num0; rb[widx][1] = den0; rb[widx][2] = num1; rb[widx][3] = den1; }
    __syncthreads();
    if (x == 0) {
        float2* nd2 = (float2*)(ws + WS_ND_);
        const int base = b * NSTR_ + sg;      // 0..127
        nd2[(kp*2    ) * (B_*NSTR_) + base] =
            make_float2(rb[0][0]+rb[1][0]+rb[2][0]+rb[3][0],
                        rb[0][1]+rb[1][1]+rb[2][1]+rb[3][1]);
        nd2[(kp*2 + 1) * (B_*NSTR_) + base] =
            make_float2(rb[0][2]+rb[1][2]+rb[2][2]+rb[3][2],
                        rb[0][3]+rb[1][3]+rb[2][3]+rb[3][3]);
        __threadfence();
        sdone = atomicAdd((unsigned*)(ws + WS_CNT_), 1u);
    }
    __syncthreads();
    if (sdone == (unsigned)(NBLK_FUSED_ - 1)) {
        __threadfence();
        if (x < 64) {
            float term = 0.f;
            if (x < K_) {
                const float2* nd2 = (const float2*)(ws + WS_ND_);
                float ns = 0.f, ds = 0.f;
                for (int i = 0; i < B_*NSTR_; ++i) {
                    const float2 v = nd2[x * (B_*NSTR_) + i];
                    ns += v.x; ds += v.y;
                }
                term = fabsf(ns / (ds + 1e-6f));
            }
            for (int o = 32; o > 0; o >>= 1) term += __shfl_down(term, o);
            if (x == 0) out[0] = (float)K_ - term;
        }
    }
}

extern "C" void kernel_launch(void* const* d_in, const int* in_sizes, int n_in,
                              void* d_out, int out_size, void* d_ws, size_t ws_size,
                              hipStream_t stream) {
    const float* labels = (const float*)d_in[0];
    const float* inputs = (const float*)d_in[1];
    float* ws = (float*)d_ws;   // needs WS_CNT_+1 floats ~= 62 KB

    stats_k<<<dim3(SCH_, K_ / KT_, B_), 256, 0, stream>>>(labels, inputs, ws);
    fused_k<<<NBLK_FUSED_, 256, 0, stream>>>(labels, inputs, ws, (float*)d_out);
}

// Round 11
// 203.003 us; speedup vs baseline: 1.4497x; 1.0076x over previous
//
#include <hip/hip_runtime.h>

#define B_ 16
#define K_ 20
#define H_ 256
#define W_ 256
#define HW_ (H_*W_)
#define BK_ (B_*K_)
#define TH_ 64          // rows per BLOCK strip (4 strips/image)
#define BATCH_ 8        // rows per barrier phase
#define KT_ 10          // stats: classes per block (inputs re-read 2x, was 4x)
#define SCH_ 16         // stats: row-chunks (16 rows each) -> 512 blocks
#define NBLK_FUSED_ (4*K_*B_)   // fused grid = 1280 blocks

// ws layout (floats): statsP [SCH_][4][BK_] | ndP [NBLK][2] | cnt  (~92 KB)
#define WS_ND_   (SCH_*4*BK_)
#define WS_CNT_  (WS_ND_ + 2*NBLK_FUSED_)

// Gaussian taps exp(-d^2/50), d=1..4 (symmetric: 4 distinct + center 1.0)
#define G1T 0.980198673f
#define G2T 0.923116346f
#define G3T 0.835270211f
#define G4T 0.726149037f

__device__ __forceinline__ float rfl(float v) {   // force value into SGPR
    return __int_as_float(__builtin_amdgcn_readfirstlane(__float_as_int(v)));
}

// ---------------------------------------------------------------------------
// stats_k: per-(b,k) sums of labels and labels*inputs_c as per-chunk partials.
// KT=10: one block covers 10 classes from ONE pass over its input chunk
// (inputs re-read 2x total instead of 4x; labels still read exactly once).
// grid (SCH_=16, 2, B_=16) = 512 blocks. float4 loads.
// ---------------------------------------------------------------------------
__global__ __launch_bounds__(256) void stats_k(const float* __restrict__ labels,
                                               const float* __restrict__ inputs,
                                               float* __restrict__ ws) {
    const int x = threadIdx.x;
    const int chunk = blockIdx.x;
    const int kt = blockIdx.y;          // 0..1
    const int b  = blockIdx.z;
    const int k0 = kt * KT_;
    if (chunk == 0 && kt == 0 && b == 0 && x == 0)
        ((unsigned*)(ws + WS_CNT_))[0] = 0u;   // reset fused completion counter

    const int cbase = chunk * (16 * W_ / 4);
    const float4* in0 = (const float4*)inputs + (size_t)b * 3 * (HW_/4) + cbase;
    const float4* in1 = in0 + (HW_/4);
    const float4* in2 = in1 + (HW_/4);
    const float4* lb  = (const float4*)labels + (size_t)(b * K_ + k0) * (HW_/4) + cbase;

    float acc[KT_][4];
#pragma unroll
    for (int kk = 0; kk < KT_; ++kk)
        acc[kk][0] = acc[kk][1] = acc[kk][2] = acc[kk][3] = 0.f;

#pragma unroll
    for (int it = 0; it < 4; ++it) {
        const int idx = it * 256 + x;
        const float4 a0 = in0[idx];
        const float4 a1 = in1[idx];
        const float4 a2 = in2[idx];
#pragma unroll
        for (int kk = 0; kk < KT_; ++kk) {
            const float4 l = lb[kk * (HW_/4) + idx];
            acc[kk][0] += (l.x + l.y) + (l.z + l.w);
            acc[kk][1] += fmaf(l.w, a0.w, fmaf(l.z, a0.z, fmaf(l.y, a0.y, l.x * a0.x)));
            acc[kk][2] += fmaf(l.w, a1.w, fmaf(l.z, a1.z, fmaf(l.y, a1.y, l.x * a1.x)));
            acc[kk][3] += fmaf(l.w, a2.w, fmaf(l.z, a2.z, fmaf(l.y, a2.y, l.x * a2.x)));
        }
    }

#pragma unroll
    for (int kk = 0; kk < KT_; ++kk)
#pragma unroll
        for (int q = 0; q < 4; ++q)
            for (int o = 32; o > 0; o >>= 1)
                acc[kk][q] += __shfl_down(acc[kk][q], o);

    __shared__ float sred[4][KT_][4];
    const int widx = x >> 6, lane = x & 63;
    if (lane == 0)
#pragma unroll
        for (int kk = 0; kk < KT_; ++kk)
#pragma unroll
            for (int q = 0; q < 4; ++q) sred[widx][kk][q] = acc[kk][q];
    __syncthreads();
    if (x < KT_ * 4) {
        const int kk = x >> 2, q = x & 3;
        const float v = sred[0][kk][q] + sred[1][kk][q] + sred[2][kk][q] + sred[3][kk][q];
        ws[(chunk * 4 + q) * BK_ + b * K_ + k0 + kk] = v;
    }
}

// ---------------------------------------------------------------------------
// fused_k: round-8 body (validated 72 µs, 60 VGPR) with ONE change:
// FLOAT2 ROW-PAIR LDS PACKING. v-blurred values of rows (2j,2j+1) stored as
// one float2 -> h-blur reads 9 x ds_read_b64 per row-PAIR (4.5 reads/row vs
// 9) and writes 4 x ds_write_b64 per batch (vs 8). x*8 addresses are 8B
// aligned (b64 guaranteed); 2-lane/bank aliasing is free (m136).
//   num = sum (l*w)*blur(l),  den = sum w*blur(l)   (adjoint, G symmetric)
// Raw s_barrier (lgkmcnt-only drain): global prefetch loads survive the
// barrier; counted vmcnt at first use (validated round 8).
// grid: 1280 blocks 1D, bijective XCD-chunk swizzle (1280 % 8 == 0).
// ---------------------------------------------------------------------------
#define CAT(m) (((m) < 8) ? ring[(m)&7] : PL[(m)&7])

__global__ __launch_bounds__(256) void fused_k(const float* __restrict__ labels,
                                               const float* __restrict__ inputs,
                                               float* __restrict__ ws,
                                               float* __restrict__ out) {
    const int x = threadIdx.x;            // column
    const int bid = blockIdx.x;
    const int swz = (bid & 7) * (NBLK_FUSED_ / 8) + (bid >> 3);
    const int b   = swz / (4 * K_);
    const int rem = swz - b * (4 * K_);
    const int k   = rem >> 2;
    const int sg  = rem & 3;
    const int bk  = b * K_ + k;
    const int r0  = sg * TH_;

    // ---- class mean from stats partials (uniform -> SGPRs) ----
    float s0 = 0.f, s1 = 0.f, s2 = 0.f, s3 = 0.f;
#pragma unroll
    for (int c = 0; c < SCH_; ++c) {
        const float* p = ws + c * 4 * BK_;
        s0 += p[bk]; s1 += p[BK_ + bk]; s2 += p[2*BK_ + bk]; s3 += p[3*BK_ + bk];
    }
    const float dnv = s0 + 1e-5f * (float)HW_;
    const float c0 = s1 / dnv, c1 = s2 / dnv, c2 = s3 / dnv;
    const float tc0 = rfl(2.f * c0), tc1 = rfl(2.f * c1), tc2 = rfl(2.f * c2);
    const float m2v = rfl(c0*c0 + c1*c1 + c2*c2);

    const float* lb  = labels + (size_t)bk * HW_;
    const float* i0p = inputs + (size_t)b * 3 * HW_;
    const float* i1p = i0p + HW_;
    const float* i2p = i1p + HW_;

    // [buf][row-pair][col]: rows (2j2, 2j2+1) packed as float2
    __shared__ float2 sv[2][BATCH_/2][W_ + 8];   // pads [0..3], [W+4..W+7]
    if (x < 64) {                                 // 2 buf x 4 pairs x 8 pad cols
        const int bu = x >> 5, j2 = (x >> 3) & 3, p = x & 7;
        const int col = (p < 4) ? p : (W_ + p);
        sv[bu][j2][col] = make_float2(0.f, 0.f);
    }

    // ---- prologue state ----
    float ring[8], PL[8], PW[8];
#pragma unroll
    for (int i = 0; i < 8; ++i) {             // rows r0-4 .. r0+3
        const int gr = r0 - 4 + i;
        ring[i] = (gr >= 0) ? lb[gr * W_ + x] : 0.f;
    }
#pragma unroll
    for (int i = 0; i < 8; ++i)               // rows r0+4 .. r0+11 (in range)
        PL[i] = lb[(r0 + 4 + i) * W_ + x];
#pragma unroll
    for (int i = 0; i < 8; ++i) {             // weights rows r0 .. r0+7
        const int r = r0 + i;
        const float a0 = i0p[r * W_ + x], a1 = i1p[r * W_ + x], a2 = i2p[r * W_ + x];
        const float d = fmaf(a0, a0 - tc0, fmaf(a1, a1 - tc1, fmaf(a2, a2 - tc2, m2v)));
        PW[i] = __expf(-d * d);               // SIGMA_2 = 1
    }
    __syncthreads();                          // pads visible (full sync, once)

    float num = 0.f, den = 0.f;
#pragma unroll 1
    for (int bt = 0; bt < TH_ / BATCH_; ++bt) {
        const int R = r0 + bt * BATCH_;
        const int bf = bt & 1;
        // ---- 1. issue next-batch loads (stay in flight across the barrier) --
        float NL[8];
#pragma unroll
        for (int i = 0; i < 8; ++i) {         // labels rows R+12..R+19, 0 if OOB
            const int gr = R + 12 + i;
            NL[i] = (gr < H_) ? lb[gr * W_ + x] : 0.f;
        }
        float a0v[8], a1v[8], a2v[8];
#pragma unroll
        for (int i = 0; i < 8; ++i) {         // inputs rows R+8..R+15 (clamped; OOB unused)
            int r = R + 8 + i; r = (r < H_) ? r : H_ - 1;
            a0v[i] = i0p[r * W_ + x]; a1v[i] = i1p[r * W_ + x]; a2v[i] = i2p[r * W_ + x];
        }
        // ---- 2. vertical 9-tap for 8 rows (pairs packed) -> LDS ----
#pragma unroll
        for (int j2 = 0; j2 < 4; ++j2) {
            const int j = 2 * j2;
            const float v0 = fmaf(G4T, CAT(j) + CAT(j+8),
                             fmaf(G3T, CAT(j+1) + CAT(j+7),
                             fmaf(G2T, CAT(j+2) + CAT(j+6),
                             fmaf(G1T, CAT(j+3) + CAT(j+5), CAT(j+4)))));
            const float v1 = fmaf(G4T, CAT(j+1) + CAT(j+9),
                             fmaf(G3T, CAT(j+2) + CAT(j+8),
                             fmaf(G2T, CAT(j+3) + CAT(j+7),
                             fmaf(G1T, CAT(j+4) + CAT(j+6), CAT(j+5)))));
            sv[bf][j2][4 + x] = make_float2(v0, v1);
        }
        // ---- 3. RAW barrier: drain LDS only; global loads stay in flight ----
        asm volatile("s_waitcnt lgkmcnt(0)" ::: "memory");
        __builtin_amdgcn_s_barrier();
        asm volatile("" ::: "memory");
        // ---- 4. h-blur + combine, two rows per pass (9 b64 reads/pair) ----
#pragma unroll
        for (int j2 = 0; j2 < 4; ++j2) {
            const int j = 2 * j2;
            const float2* s = &sv[bf][j2][x];
            const float2 t0 = s[0], t1 = s[1], t2 = s[2], t3 = s[3], t4 = s[4],
                         t5 = s[5], t6 = s[6], t7 = s[7], t8 = s[8];
            const float blx = fmaf(G4T, t0.x + t8.x,
                              fmaf(G3T, t1.x + t7.x,
                              fmaf(G2T, t2.x + t6.x,
                              fmaf(G1T, t3.x + t5.x, t4.x))));
            const float bly = fmaf(G4T, t0.y + t8.y,
                              fmaf(G3T, t1.y + t7.y,
                              fmaf(G2T, t2.y + t6.y,
                              fmaf(G1T, t3.y + t5.y, t4.y))));
            const float u0 = PW[j]   * blx;
            const float u1 = PW[j+1] * bly;
            den += u0 + u1;
            num = fmaf(CAT(j+4), u0, fmaf(CAT(j+5), u1, num));
        }
        // ---- 5. next weights + rotate state (first use of step-1 loads) ----
#pragma unroll
        for (int i = 0; i < 8; ++i) {
            const float d = fmaf(a0v[i], a0v[i] - tc0,
                            fmaf(a1v[i], a1v[i] - tc1,
                            fmaf(a2v[i], a2v[i] - tc2, m2v)));
            const float w = __expf(-d * d);
            ring[i] = PL[i]; PL[i] = NL[i]; PW[i] = w;
        }
    }

    // ---- block reduce + last-block finalize ----
    const int widx = x >> 6, lane = x & 63;
    for (int o = 32; o > 0; o >>= 1) { num += __shfl_down(num, o); den += __shfl_down(den, o); }
    __shared__ float rb[4][2];
    __shared__ unsigned sdone;
    __syncthreads();
    if (lane == 0) { rb[widx][0] = num; rb[widx][1] = den; }
    __syncthreads();
    if (x == 0) {
        const float fn = rb[0][0] + rb[1][0] + rb[2][0] + rb[3][0];
        const float fd = rb[0][1] + rb[1][1] + rb[2][1] + rb[3][1];
        float2* nd2 = (float2*)(ws + WS_ND_);
        nd2[k * 64 + b * 4 + sg] = make_float2(fn, fd);
        __threadfence();
        sdone = atomicAdd((unsigned*)(ws + WS_CNT_), 1u);
    }
    __syncthreads();
    if (sdone == (unsigned)(NBLK_FUSED_ - 1)) {
        __threadfence();
        if (x < 64) {
            float term = 0.f;
            if (x < K_) {
                const float2* nd2 = (const float2*)(ws + WS_ND_);
                float ns = 0.f, ds = 0.f;
                for (int i = 0; i < 64; ++i) {
                    const float2 v = nd2[x * 64 + i];
                    ns += v.x; ds += v.y;
                }
                term = fabsf(ns / (ds + 1e-6f));
            }
            for (int o = 32; o > 0; o >>= 1) term += __shfl_down(term, o);
            if (x == 0) out[0] = (float)K_ - term;
        }
    }
}

extern "C" void kernel_launch(void* const* d_in, const int* in_sizes, int n_in,
                              void* d_out, int out_size, void* d_ws, size_t ws_size,
                              hipStream_t stream) {
    const float* labels = (const float*)d_in[0];
    const float* inputs = (const float*)d_in[1];
    float* ws = (float*)d_ws;   // needs WS_CNT_+1 floats ~= 92 KB

    stats_k<<<dim3(SCH_, K_ / KT_, B_), 256, 0, stream>>>(labels, inputs, ws);
    fused_k<<<NBLK_FUSED_, 256, 0, stream>>>(labels, inputs, ws, (float*)d_out);
}